// Round 2
// baseline (7136.848 us; speedup 1.0000x reference)
//
#include <hip/hip_runtime.h>
#include <stdint.h>

#define Bb 32
#define Tt 64
#define Ee 300
#define Zz 1100
#define Hh 800
#define Vv 32000
#define INn 1400
#define G4 3200   // 4*H

typedef __attribute__((ext_vector_type(8))) short short8;
typedef __attribute__((ext_vector_type(4))) float f32x4;

__device__ __forceinline__ float sigm(float x){ return 1.f/(1.f+__expf(-x)); }
__device__ __forceinline__ unsigned short f2bf(float f){
  unsigned u=__float_as_uint(f);
  unsigned r=(u + 0x7fffu + ((u>>16)&1u))>>16;
  return (unsigned short)r;
}
__device__ __forceinline__ float bflo(unsigned u){ return __uint_as_float(u<<16); }
__device__ __forceinline__ float bfhi(unsigned u){ return __uint_as_float(u & 0xffff0000u); }

// ---------------- fp32 -> bf16 bulk convert ----------------
__global__ __launch_bounds__(256) void k_f2b(const float* __restrict__ in,
                                             unsigned short* __restrict__ out, long n){
  long i=((long)blockIdx.x*256+threadIdx.x)*4;
  long stride=(long)gridDim.x*256*4;
  for(;i<n;i+=stride){
    float4 v=*(const float4*)(in+i);
    ushort4 o; o.x=f2bf(v.x); o.y=f2bf(v.y); o.z=f2bf(v.z); o.w=f2bf(v.w);
    *(ushort4*)(out+i)=o;
  }
}

// ---------------- z @ Wz.T + b0  ->  zx[B][4H] ----------------
__global__ __launch_bounds__(256) void k_zproj(const float* __restrict__ z,
    const float* __restrict__ Wih0, const float* __restrict__ b0, float* __restrict__ zx){
  int b=blockIdx.y; int n=blockIdx.x*256+threadIdx.x;
  __shared__ float zs[Zz];
  for(int i=threadIdx.x;i<Zz;i+=256) zs[i]=z[(size_t)b*Zz+i];
  __syncthreads();
  if(n>=G4) return;
  const float* w = Wih0 + (size_t)n*INn + Ee;
  float acc=b0[n];
  for(int k=0;k<Zz;k+=4){
    float4 w4=*(const float4*)(w+k);
    float4 z4=*(const float4*)(zs+k);
    acc += w4.x*z4.x+w4.y*z4.y+w4.z*z4.z+w4.w*z4.w;
  }
  zx[(size_t)b*G4+n]=acc;
}

// ---------------- dec @ Wd.T + zx -> gx0[B][T][4H] ----------------
__global__ __launch_bounds__(256) void k_gx0(const float* __restrict__ dec,
    const float* __restrict__ Wih0, const float* __restrict__ zx, float* __restrict__ gx){
  int b=blockIdx.y, t0=blockIdx.x*4;
  __shared__ float ds[4][Ee];
  for(int i=threadIdx.x;i<4*Ee;i+=256){ int tt=i/Ee, k=i-tt*Ee; ds[tt][k]=dec[((size_t)b*Tt+t0+tt)*Ee+k]; }
  __syncthreads();
  for(int n=threadIdx.x;n<G4;n+=256){
    const float* w=Wih0+(size_t)n*INn;
    float a0=0,a1=0,a2=0,a3=0;
    for(int k=0;k<Ee;k+=4){
      float4 wv=*(const float4*)(w+k);
      float4 d0=*(const float4*)(&ds[0][k]);
      float4 d1=*(const float4*)(&ds[1][k]);
      float4 d2=*(const float4*)(&ds[2][k]);
      float4 d3=*(const float4*)(&ds[3][k]);
      a0+=wv.x*d0.x+wv.y*d0.y+wv.z*d0.z+wv.w*d0.w;
      a1+=wv.x*d1.x+wv.y*d1.y+wv.z*d1.z+wv.w*d1.w;
      a2+=wv.x*d2.x+wv.y*d2.y+wv.z*d2.z+wv.w*d2.w;
      a3+=wv.x*d3.x+wv.y*d3.y+wv.z*d3.z+wv.w*d3.w;
    }
    float zv=zx[(size_t)b*G4+n];
    size_t base=((size_t)b*Tt+t0)*G4+n;
    gx[base]=a0+zv; gx[base+G4]=a1+zv; gx[base+2*(size_t)G4]=a2+zv; gx[base+3*(size_t)G4]=a3+zv;
  }
}

// ---------------- attention body (step t), handles 2 batch rows ----------------
__device__ void attn_body(int b0_, int t, const float* __restrict__ g1,
                          const float* __restrict__ c1p, float* __restrict__ c1o,
                          const float* __restrict__ enc, unsigned short* __restrict__ outs){
  __shared__ float h1s[2][Hh];
  __shared__ float sc[2][Tt];
  int tid=threadIdx.x;
  for(int i=tid;i<2*Hh;i+=256){
    int bb=(i>=Hh); int j=i-bb*Hh; int b=b0_+bb;
    size_t g=(size_t)b*G4;
    float gi=g1[g+j], gf=g1[g+Hh+j], gg=g1[g+2*Hh+j], go=g1[g+3*Hh+j];
    float cn=sigm(gf)*c1p[(size_t)b*Hh+j]+sigm(gi)*tanhf(gg);
    c1o[(size_t)b*Hh+j]=cn;
    h1s[bb][j]=sigm(go)*tanhf(cn);
  }
  __syncthreads();
  if(tid<128){
    int bb=tid>>6, s=tid&63, b=b0_+bb;
    const float* e=enc+((size_t)b*Tt+s)*Hh;
    float acc=0;
    for(int k=0;k<Hh;k+=4){
      float4 e4=*(const float4*)(e+k);
      float4 h4=*(const float4*)(&h1s[bb][k]);
      acc+=e4.x*h4.x+e4.y*h4.y+e4.z*h4.z+e4.w*h4.w;
    }
    sc[bb][s]=acc;
  }
  __syncthreads();
  if(tid<128){
    int bb=tid>>6, s=tid&63;
    float v=sc[bb][s];
    float m=v;
    for(int off=32;off;off>>=1) m=fmaxf(m,__shfl_xor(m,off));
    float p=__expf(v-m);
    float su=p;
    for(int off=32;off;off>>=1) su+=__shfl_xor(su,off);
    sc[bb][s]=p/su;
  }
  __syncthreads();
  for(int i=tid;i<2*Hh;i+=256){
    int bb=(i>=Hh); int j=i-bb*Hh; int b=b0_+bb;
    float acc=0;
    const float* e=enc+(size_t)b*Tt*Hh+j;
    #pragma unroll 4
    for(int s=0;s<Tt;s++) acc+=sc[bb][s]*e[(size_t)s*Hh];
    size_t ob=((size_t)b*Tt+t)*(2*Hh);
    outs[ob+j]=f2bf(h1s[bb][j]);
    outs[ob+Hh+j]=f2bf(acc);
  }
}

// ---------------- cell0(t): gates0 = gx0[:,t,:] + h0(t-1) @ Whh0^T ; bx==13 -> attn(t-1) ----------------
__global__ __launch_bounds__(256) void k_cell0(
  const unsigned short* __restrict__ Whh0b, const float* __restrict__ gx,
  const float* __restrict__ g0prev, const float* __restrict__ c0prev,
  float* __restrict__ g0out,
  const float* __restrict__ g1prev, const float* __restrict__ c1prev_attn,
  float* __restrict__ c1out_attn, const float* __restrict__ enc,
  unsigned short* __restrict__ outs, int t)
{
  int b0_=blockIdx.y*2;
  if(blockIdx.x==13){
    if(t>0) attn_body(b0_, t-1, g1prev, c1prev_attn, c1out_attn, enc, outs);
    return;
  }
  __shared__ float hs[2][Hh];
  for(int i=threadIdx.x;i<2*Hh;i+=256){
    int bb=(i>=Hh); int j=i-bb*Hh; int b=b0_+bb;
    float o=g0prev[(size_t)b*G4+3*Hh+j];
    float c=c0prev[(size_t)b*Hh+j];
    hs[bb][j]=sigm(o)*tanhf(c);
  }
  __syncthreads();
  int n=blockIdx.x*256+threadIdx.x;
  if(n>=G4) return;
  const uint4* w=(const uint4*)(Whh0b+(size_t)n*Hh);
  float a0=0,a1=0;
  for(int k8=0;k8<Hh/8;k8++){
    uint4 u=w[k8];
    int k=k8*8;
    float w0=bflo(u.x),w1=bfhi(u.x),w2=bflo(u.y),w3=bfhi(u.y),
          w4=bflo(u.z),w5=bfhi(u.z),w6=bflo(u.w),w7=bfhi(u.w);
    float4 ha=*(const float4*)(&hs[0][k]); float4 hb=*(const float4*)(&hs[0][k+4]);
    a0+=w0*ha.x+w1*ha.y+w2*ha.z+w3*ha.w + w4*hb.x+w5*hb.y+w6*hb.z+w7*hb.w;
    ha=*(const float4*)(&hs[1][k]); hb=*(const float4*)(&hs[1][k+4]);
    a1+=w0*ha.x+w1*ha.y+w2*ha.z+w3*ha.w + w4*hb.x+w5*hb.y+w6*hb.z+w7*hb.w;
  }
  g0out[(size_t)(b0_+0)*G4+n]=a0+gx[((size_t)(b0_+0)*Tt+t)*G4+n];
  g0out[(size_t)(b0_+1)*G4+n]=a1+gx[((size_t)(b0_+1)*Tt+t)*G4+n];
}

// ---------------- cell1(t): gates1 = b1 + h0(t) @ Wih1^T + h1(t-1) @ Whh1^T ----------------
__global__ __launch_bounds__(256) void k_cell1(
  const unsigned short* __restrict__ Wih1b, const unsigned short* __restrict__ Whh1b,
  const float* __restrict__ b1,
  const float* __restrict__ g0cur, const float* __restrict__ c0prev, float* __restrict__ c0out,
  const float* __restrict__ g1prev, const float* __restrict__ c1prev,
  float* __restrict__ g1out)
{
  int b0_=blockIdx.y*2;
  __shared__ float hs0[2][Hh], hs1[2][Hh];
  for(int i=threadIdx.x;i<2*Hh;i+=256){
    int bb=(i>=Hh); int j=i-bb*Hh; int b=b0_+bb;
    size_t g=(size_t)b*G4;
    float gi=g0cur[g+j], gf=g0cur[g+Hh+j], gg=g0cur[g+2*Hh+j], go=g0cur[g+3*Hh+j];
    float cn=sigm(gf)*c0prev[(size_t)b*Hh+j]+sigm(gi)*tanhf(gg);
    c0out[(size_t)b*Hh+j]=cn;                      // duplicate-identical across bx: benign
    hs0[bb][j]=sigm(go)*tanhf(cn);
    float o1=g1prev[g+3*Hh+j];
    hs1[bb][j]=sigm(o1)*tanhf(c1prev[(size_t)b*Hh+j]);
  }
  __syncthreads();
  int n=blockIdx.x*256+threadIdx.x;
  if(n>=G4) return;
  float a0=0,a1=0;
  {
    const uint4* w=(const uint4*)(Wih1b+(size_t)n*Hh);
    for(int k8=0;k8<Hh/8;k8++){
      uint4 u=w[k8]; int k=k8*8;
      float w0=bflo(u.x),w1=bfhi(u.x),w2=bflo(u.y),w3=bfhi(u.y),
            w4=bflo(u.z),w5=bfhi(u.z),w6=bflo(u.w),w7=bfhi(u.w);
      float4 ha=*(const float4*)(&hs0[0][k]); float4 hb=*(const float4*)(&hs0[0][k+4]);
      a0+=w0*ha.x+w1*ha.y+w2*ha.z+w3*ha.w + w4*hb.x+w5*hb.y+w6*hb.z+w7*hb.w;
      ha=*(const float4*)(&hs0[1][k]); hb=*(const float4*)(&hs0[1][k+4]);
      a1+=w0*ha.x+w1*ha.y+w2*ha.z+w3*ha.w + w4*hb.x+w5*hb.y+w6*hb.z+w7*hb.w;
    }
  }
  {
    const uint4* w=(const uint4*)(Whh1b+(size_t)n*Hh);
    for(int k8=0;k8<Hh/8;k8++){
      uint4 u=w[k8]; int k=k8*8;
      float w0=bflo(u.x),w1=bfhi(u.x),w2=bflo(u.y),w3=bfhi(u.y),
            w4=bflo(u.z),w5=bfhi(u.z),w6=bflo(u.w),w7=bfhi(u.w);
      float4 ha=*(const float4*)(&hs1[0][k]); float4 hb=*(const float4*)(&hs1[0][k+4]);
      a0+=w0*ha.x+w1*ha.y+w2*ha.z+w3*ha.w + w4*hb.x+w5*hb.y+w6*hb.z+w7*hb.w;
      ha=*(const float4*)(&hs1[1][k]); hb=*(const float4*)(&hs1[1][k+4]);
      a1+=w0*ha.x+w1*ha.y+w2*ha.z+w3*ha.w + w4*hb.x+w5*hb.y+w6*hb.z+w7*hb.w;
    }
  }
  float bias=b1[n];
  g1out[(size_t)(b0_+0)*G4+n]=a0+bias;
  g1out[(size_t)(b0_+1)*G4+n]=a1+bias;
}

// ---------------- final: attn(63) + final h/c states -> d_out tail ----------------
__global__ __launch_bounds__(256) void k_final(
  const float* __restrict__ g0f, const float* __restrict__ c0f,
  const float* __restrict__ g1f, const float* __restrict__ c1_62,
  float* __restrict__ c1_w, const float* __restrict__ enc,
  unsigned short* __restrict__ outs, float* __restrict__ dout)
{
  int bx=blockIdx.x;
  if(bx<16){ attn_body(bx*2, 63, g1f, c1_62, c1_w, enc, outs); return; }
  int i=(bx-16)*256+threadIdx.x;
  if(i>=2*Bb*Hh) return;
  int l=i/(Bb*Hh); int r=i-l*(Bb*Hh); int b=r/Hh; int j=r-b*Hh;
  size_t tail=(size_t)Bb*Tt*Vv;
  float hv, cv;
  if(l==0){
    cv=c0f[(size_t)b*Hh+j];
    hv=sigm(g0f[(size_t)b*G4+3*Hh+j])*tanhf(cv);
  } else {
    size_t g=(size_t)b*G4;
    float gi=g1f[g+j],gf=g1f[g+Hh+j],gg=g1f[g+2*Hh+j],go=g1f[g+3*Hh+j];
    cv=sigm(gf)*c1_62[(size_t)b*Hh+j]+sigm(gi)*tanhf(gg);
    hv=sigm(go)*tanhf(cv);
  }
  dout[tail + (size_t)l*(Bb*Hh) + (size_t)b*Hh + j]=hv;
  dout[tail + 2*(size_t)Bb*Hh + (size_t)l*(Bb*Hh) + (size_t)b*Hh + j]=cv;
}

// ---------------- output projection: C[2048][32000] = A[2048][1600] @ B[32000][1600]^T + bias ----------------
#define BM 128
#define BN 128
#define BK 64
#define LDS_STRIDE 72   // 64 + 8 bf16 pad: kills the 128B-stride bank conflict

__global__ __launch_bounds__(256) void k_gemm(
  const unsigned short* __restrict__ A, const unsigned short* __restrict__ Bm,
  const float* __restrict__ bias, float* __restrict__ C)
{
  __shared__ unsigned short As[BM*LDS_STRIDE];
  __shared__ unsigned short Bs[BN*LDS_STRIDE];
  const int tid=threadIdx.x, wave=tid>>6, lane=tid&63;
  const int m0=blockIdx.y*BM, n0=blockIdx.x*BN;
  const int wm=(wave>>1)*64, wn=(wave&1)*64;
  const int K=2*Hh, N=Vv;
  f32x4 acc[4][4];
  #pragma unroll
  for(int i=0;i<4;i++)
    #pragma unroll
    for(int j=0;j<4;j++) acc[i][j]=(f32x4){0.f,0.f,0.f,0.f};

  const char* Agb=(const char*)A;
  const char* Bgb=(const char*)Bm;
  char* Asb=(char*)As; char* Bsb=(char*)Bs;

  for(int k0=0;k0<K;k0+=BK){
    uint4 av[4], bv[4];
    #pragma unroll
    for(int p=0;p<4;p++){
      int flat=p*4096+tid*16;
      int row=flat>>7, cb=flat&127;
      av[p]=*(const uint4*)(Agb + ((size_t)(m0+row)*K + k0)*2 + cb);
      bv[p]=*(const uint4*)(Bgb + ((size_t)(n0+row)*K + k0)*2 + cb);
    }
    __syncthreads();   // previous iter's compute done before overwriting LDS
    #pragma unroll
    for(int p=0;p<4;p++){
      int flat=p*4096+tid*16;
      int row=flat>>7, cb=flat&127;
      *(uint4*)(Asb + row*(LDS_STRIDE*2) + cb)=av[p];
      *(uint4*)(Bsb + row*(LDS_STRIDE*2) + cb)=bv[p];
    }
    __syncthreads();
    #pragma unroll
    for(int kk=0;kk<2;kk++){
      short8 af[4], bfr[4];
      int colb=kk*64 + (lane>>4)*16;
      #pragma unroll
      for(int mi=0;mi<4;mi++){
        int row=wm+mi*16+(lane&15);
        af[mi]=*(const short8*)(Asb + row*(LDS_STRIDE*2) + colb);
      }
      #pragma unroll
      for(int ni=0;ni<4;ni++){
        int row=wn+ni*16+(lane&15);
        bfr[ni]=*(const short8*)(Bsb + row*(LDS_STRIDE*2) + colb);
      }
      #pragma unroll
      for(int mi=0;mi<4;mi++)
        #pragma unroll
        for(int ni=0;ni<4;ni++)
          acc[mi][ni]=__builtin_amdgcn_mfma_f32_16x16x32_bf16(af[mi],bfr[ni],acc[mi][ni],0,0,0);
    }
  }
  #pragma unroll
  for(int ni=0;ni<4;ni++){
    int col=n0+wn+ni*16+(lane&15);
    float bvs=bias[col];
    #pragma unroll
    for(int mi=0;mi<4;mi++){
      int row=m0+wm+mi*16+((lane>>4)<<2);
      #pragma unroll
      for(int r=0;r<4;r++)
        C[(size_t)(row+r)*N+col]=acc[mi][ni][r]+bvs;
    }
  }
}

extern "C" void kernel_launch(void* const* d_in, const int* in_sizes, int n_in,
                              void* d_out, int out_size, void* d_ws, size_t ws_size,
                              hipStream_t stream) {
  const float* dec  =(const float*)d_in[0];
  const float* z    =(const float*)d_in[1];
  const float* enc  =(const float*)d_in[2];
  const float* Wih0 =(const float*)d_in[4];
  const float* Whh0 =(const float*)d_in[5];
  const float* b0   =(const float*)d_in[6];
  const float* Wih1 =(const float*)d_in[7];
  const float* Whh1 =(const float*)d_in[8];
  const float* b1   =(const float*)d_in[9];
  const float* Wout =(const float*)d_in[10];
  const float* bout =(const float*)d_in[11];
  float* dout=(float*)d_out;

  // workspace layout
  float* gx0 = (float*)d_ws;                 // 6,553,600
  float* zx  = gx0 + (size_t)6553600;        // 102,400
  float* g0t = zx  + 102400;                 // 2 x 102,400
  float* g1t = g0t + 204800;                 // 2 x 102,400
  float* c0s = g1t + 204800;                 // 2 x 25,600
  float* c1s = c0s + 51200;                  // 2 x 25,600
  unsigned short* outs  = (unsigned short*)(c1s + 51200);       // 2048*1600 bf16
  unsigned short* Wob   = outs + (size_t)2048*1600;             // 32000*1600 bf16
  unsigned short* Whh0b = Wob + (size_t)32000*1600;             // 2,560,000
  unsigned short* Wih1b = Whh0b + 2560000;
  unsigned short* Whh1b = Wih1b + 2560000;

  // zero-init the "t = -1" slots (slot 1)
  hipMemsetAsync(g0t+102400, 0, 102400*sizeof(float), stream);
  hipMemsetAsync(g1t+102400, 0, 102400*sizeof(float), stream);
  hipMemsetAsync(c0s+25600, 0, 25600*sizeof(float), stream);
  hipMemsetAsync(c1s+25600, 0, 25600*sizeof(float), stream);

  // weight conversions to bf16
  k_f2b<<<2048,256,0,stream>>>(Wout,  Wob,   (long)32000*1600);
  k_f2b<<<512,256,0,stream>>>(Whh0, Whh0b, 2560000);
  k_f2b<<<512,256,0,stream>>>(Wih1, Wih1b, 2560000);
  k_f2b<<<512,256,0,stream>>>(Whh1, Whh1b, 2560000);

  // time-parallel input projections
  k_zproj<<<dim3(13,32),256,0,stream>>>(z, Wih0, b0, zx);
  k_gx0<<<dim3(16,32),256,0,stream>>>(dec, Wih0, zx, gx0);

  // recurrence: 2 kernels per step (attn for t-1 rides in cell0's extra blocks)
  for(int t=0;t<Tt;t++){
    int cur=t&1, prev=1-cur;
    k_cell0<<<dim3(14,16),256,0,stream>>>(Whh0b, gx0,
        g0t+(size_t)prev*102400, c0s+(size_t)prev*25600,
        g0t+(size_t)cur*102400,
        g1t+(size_t)prev*102400, c1s+(size_t)cur*25600,   // attn(t-1): reads c1(t-2)=slot cur
        c1s+(size_t)prev*25600,                           // attn(t-1): writes c1(t-1)=slot prev
        enc, outs, t);
    k_cell1<<<dim3(13,16),256,0,stream>>>(Wih1b, Whh1b, b1,
        g0t+(size_t)cur*102400, c0s+(size_t)prev*25600, c0s+(size_t)cur*25600,
        g1t+(size_t)prev*102400, c1s+(size_t)prev*25600,
        g1t+(size_t)cur*102400);
  }

  // attn(63) + final states
  k_final<<<dim3(216),256,0,stream>>>(g0t+102400, c0s+25600,
      g1t+102400, c1s /*c1(62) slot0*/, c1s+25600, enc, outs, dout);

  // output projection
  k_gemm<<<dim3(Vv/BN, (Bb*Tt)/BM),256,0,stream>>>(outs, Wob, bout, dout);
}